// Round 1
// baseline (1260.992 us; speedup 1.0000x reference)
//
#include <hip/hip_runtime.h>
#include <stdint.h>

// SSD multibox head: 6 scales, per scale a fused (loc||conf) 3x3 SAME conv as
// implicit GEMM  C[M,N] = im2col(x)[M,K] * W^T[K,N],  M=B*H*W, K=Cin*9.
// bf16 MFMA (16x16x32), fp32 accumulate, epilogue scatters into the
// reshape(4,-1)/transpose/concat output layout directly.

#define BM 128
#define BN 128
#define BK 64
#define NTH 256
#define ATOT 8732
#define LOCTOT 279424   // 8*8732*4

typedef short short8 __attribute__((ext_vector_type(8)));
typedef float f32x4 __attribute__((ext_vector_type(4)));

struct ScaleP {
  const float *x, *lw, *lb, *cw, *cb;
  int C, H, W, nb, M, K, Nloc, Ntot, abase, mtiles, ntiles, boff;
};
struct AllP { ScaleP s[6]; };

__device__ __forceinline__ unsigned short f2bf(float f) {
  unsigned u = __float_as_uint(f);
  u += 0x7fffu + ((u >> 16) & 1u);   // RNE
  return (unsigned short)(u >> 16);
}

__global__ __launch_bounds__(NTH)
void mbox_gemm(AllP P, float* __restrict__ out) {
  __shared__ __align__(16) unsigned short A_s[BM * BK];
  __shared__ __align__(16) unsigned short B_s[BN * BK];

  const int bid = blockIdx.x;
  int e = 0;
  #pragma unroll
  for (int i = 1; i < 6; ++i) if (bid >= P.s[i].boff) e = i;
  const ScaleP sp = P.s[e];

  const int local = bid - sp.boff;
  const int mtile = local % sp.mtiles;
  const int ntile = local / sp.mtiles;

  const int tid  = threadIdx.x;
  const int lane = tid & 63;
  const int wv   = tid >> 6;
  const int wm   = wv >> 1;   // 0..1  (wave m-half)
  const int wn   = wv & 1;    // 0..1  (wave n-half)

  const int HWp = sp.H * sp.W;

  // ---- A-staging precompute: thread owns fixed m, one 32-wide k half ----
  const int am   = (tid & 63) + ((wv & 1) << 6);  // m_loc 0..127
  const int akh  = wv >> 1;                       // k half 0/1
  const int amg  = mtile * BM + am;
  const bool amok = amg < sp.M;
  const int amc  = amok ? amg : (sp.M - 1);
  const int ab_  = (int)((unsigned)amc / (unsigned)HWp);
  const int ap   = amc - ab_ * HWp;
  const int ah   = (int)((unsigned)ap / (unsigned)sp.W);
  const int aw   = ap - ah * sp.W;
  unsigned vmask = 0;
  #pragma unroll
  for (int r = 0; r < 9; ++r) {
    int hh = ah + r / 3 - 1, ww = aw + r % 3 - 1;
    if (hh >= 0 && hh < sp.H && ww >= 0 && ww < sp.W) vmask |= (1u << r);
  }
  if (!amok) vmask = 0;
  const float* axb = sp.x + (size_t)ab_ * sp.C * HWp + ap;

  // ---- B-staging precompute: thread owns one weight row, one k half ----
  const int bn  = tid >> 1;   // 0..127
  const int bkh = tid & 1;
  const int bng = ntile * BN + bn;
  const bool bnv = bng < sp.Ntot;
  const float* wrow;
  if (bng < sp.Nloc) wrow = sp.lw + (size_t)bng * sp.K;
  else if (bnv)      wrow = sp.cw + (size_t)(bng - sp.Nloc) * sp.K;
  else               wrow = sp.lw;  // dummy, zeroed below

  f32x4 acc[4][4] = {};

  const int nK = sp.K / BK;   // K is always a multiple of 64 here
  for (int kt = 0; kt < nK; ++kt) {
    const int k0 = kt * BK;
    __syncthreads();
    // ---- stage A (im2col, k = ci*9 + r ordering) ----
    {
      int kg  = k0 + (akh << 5);
      int ci  = (int)((unsigned)kg / 9u);
      int r   = kg - ci * 9;
      int d3  = (int)((unsigned)r / 3u);
      int dw  = r - d3 * 3;
      int roff = (d3 - 1) * sp.W + (dw - 1);
      int cio  = ci * HWp;
      #pragma unroll
      for (int q = 0; q < 8; ++q) {
        unsigned long long pk = 0;
        #pragma unroll
        for (int e4 = 0; e4 < 4; ++e4) {
          bool v = (vmask >> r) & 1u;
          int o = v ? (cio + roff) : 0;
          float f = axb[o];
          unsigned short us = v ? f2bf(f) : (unsigned short)0;
          pk |= (unsigned long long)us << (16 * e4);
          bool w9 = (r == 8);
          bool w3 = (dw == 2);
          r    = w9 ? 0 : r + 1;
          cio += w9 ? HWp : 0;
          roff = w9 ? (-sp.W - 1) : (roff + (w3 ? (sp.W - 2) : 1));
          dw   = (w9 || w3) ? 0 : dw + 1;
        }
        int kl  = (akh << 5) + (q << 2);
        int idx = am * BK + (kl ^ ((am & 7) << 3));  // 16B-granular XOR swizzle
        *(unsigned long long*)&A_s[idx] = pk;
      }
    }
    // ---- stage B (weights already [N][K] row-major: k-contiguous) ----
    {
      #pragma unroll
      for (int q = 0; q < 8; ++q) {
        int kl = (bkh << 5) + (q << 2);
        float4 w4 = *(const float4*)(wrow + k0 + kl);
        unsigned long long pk = 0;
        if (bnv) {
          pk = (unsigned long long)f2bf(w4.x)
             | ((unsigned long long)f2bf(w4.y) << 16)
             | ((unsigned long long)f2bf(w4.z) << 32)
             | ((unsigned long long)f2bf(w4.w) << 48);
        }
        int idx = bn * BK + (kl ^ ((bn & 7) << 3));
        *(unsigned long long*)&B_s[idx] = pk;
      }
    }
    __syncthreads();
    // ---- MFMA: 2 k-subtiles x 4x4 fragments ----
    #pragma unroll
    for (int kk = 0; kk < 2; ++kk) {
      const int kb = (kk << 5) + ((lane >> 4) << 3);
      short8 af[4], bfr[4];
      #pragma unroll
      for (int mf = 0; mf < 4; ++mf) {
        int row = (wm << 6) + (mf << 4) + (lane & 15);
        af[mf] = *(const short8*)&A_s[row * BK + (kb ^ ((row & 7) << 3))];
      }
      #pragma unroll
      for (int nf = 0; nf < 4; ++nf) {
        int row = (wn << 6) + (nf << 4) + (lane & 15);
        bfr[nf] = *(const short8*)&B_s[row * BK + (kb ^ ((row & 7) << 3))];
      }
      #pragma unroll
      for (int mf = 0; mf < 4; ++mf)
        #pragma unroll
        for (int nf = 0; nf < 4; ++nf)
          acc[mf][nf] = __builtin_amdgcn_mfma_f32_16x16x32_bf16(
              af[mf], bfr[nf], acc[mf][nf], 0, 0, 0);
    }
  }

  // ---- epilogue: bias + scatter to (locs || labels) layout ----
  // conv channel c = i*nb + rb  ->  out[b, abase + rb*HW + p, i]
  const int l15 = lane & 15;
  const int l4  = lane >> 4;
  #pragma unroll
  for (int nf = 0; nf < 4; ++nf) {
    const int ng = ntile * BN + (wn << 6) + (nf << 4) + l15;
    const bool nvalid = ng < sp.Ntot;
    const bool isloc  = ng < sp.Nloc;
    const int n2 = isloc ? ng : (ng - sp.Nloc);
    const int ii = nvalid ? (int)((unsigned)n2 / (unsigned)sp.nb) : 0;
    const int rb = n2 - ii * sp.nb;
    const float bias = nvalid ? (isloc ? sp.lb[n2] : sp.cb[n2]) : 0.f;
    const int strd = isloc ? 4 : 81;
    const long ob0 = isloc ? 0l : (long)LOCTOT;
    #pragma unroll
    for (int mf = 0; mf < 4; ++mf) {
      #pragma unroll
      for (int rg = 0; rg < 4; ++rg) {
        const int mg = mtile * BM + (wm << 6) + (mf << 4) + (l4 << 2) + rg;
        if (nvalid && mg < sp.M) {
          const int b = (int)((unsigned)mg / (unsigned)HWp);
          const int p = mg - b * HWp;
          const int aidx = sp.abase + rb * HWp + p;
          out[ob0 + (long)(b * ATOT + aidx) * strd + ii] = acc[mf][nf][rg] + bias;
        }
      }
    }
  }
}

extern "C" void kernel_launch(void* const* d_in, const int* in_sizes, int n_in,
                              void* d_out, int out_size, void* d_ws, size_t ws_size,
                              hipStream_t stream) {
  static const int CH[6]  = {512, 1024, 512, 256, 256, 256};
  static const int HH[6]  = {38, 19, 10, 5, 3, 1};
  static const int NB_[6] = {4, 6, 6, 6, 4, 4};
  static const int ORD[6] = {1, 0, 2, 3, 4, 5};  // longest-K blocks first

  int abase[6]; int accum = 0;
  for (int s = 0; s < 6; ++s) { abase[s] = accum; accum += NB_[s] * HH[s] * HH[s]; }

  AllP P;
  int boff = 0;
  for (int oi = 0; oi < 6; ++oi) {
    int s = ORD[oi];
    ScaleP& sp = P.s[oi];
    sp.x  = (const float*)d_in[5 * s + 0];
    sp.lw = (const float*)d_in[5 * s + 1];
    sp.lb = (const float*)d_in[5 * s + 2];
    sp.cw = (const float*)d_in[5 * s + 3];
    sp.cb = (const float*)d_in[5 * s + 4];
    sp.C = CH[s]; sp.H = HH[s]; sp.W = HH[s]; sp.nb = NB_[s];
    sp.M = 8 * HH[s] * HH[s];
    sp.K = CH[s] * 9;
    sp.Nloc = NB_[s] * 4;
    sp.Ntot = NB_[s] * 85;   // nb*4 + nb*81
    sp.abase = abase[s];
    sp.mtiles = (sp.M + BM - 1) / BM;
    sp.ntiles = (sp.Ntot + BN - 1) / BN;
    sp.boff = boff;
    boff += sp.mtiles * sp.ntiles;
  }
  hipLaunchKernelGGL(mbox_gemm, dim3(boff), dim3(NTH), 0, stream, P, (float*)d_out);
}

// Round 2
// 392.636 us; speedup vs baseline: 3.2116x; 3.2116x over previous
//
#include <hip/hip_runtime.h>
#include <stdint.h>

// SSD multibox head. Round 2: K reordered as k=r*C+ci so every BK=64 chunk is
// contiguous; prep kernels build NHWC bf16 activations (xh) and [co][r*C+ci]
// bf16 padded weights (wp) in ws; GEMM stages via global_load_lds (16B) with
// source-side XOR swizzle; split-K + fp32 atomics for parallelism.

#define NTH 256
#define ATOT 8732
#define LOCTOT 279424   // 8*8732*4

typedef short short8 __attribute__((ext_vector_type(8)));
typedef float f32x4 __attribute__((ext_vector_type(4)));

__device__ __forceinline__ unsigned short f2bf(float f) {
  unsigned u = __float_as_uint(f);
  u += 0x7fffu + ((u >> 16) & 1u);   // RNE
  return (unsigned short)(u >> 16);
}

__device__ __forceinline__ void gload_lds16(const void* g, void* l) {
  __builtin_amdgcn_global_load_lds(
      (const __attribute__((address_space(1))) unsigned int*)g,
      (__attribute__((address_space(3))) unsigned int*)l, 16, 0, 0);
}

// ---------------- prep_x: NCHW f32 -> NHWC bf16 (LDS tile transpose) --------
struct PXs { const float* x; unsigned short* xh; int C, HWp, ptiles, boff; };
struct PX { PXs s[6]; };

__global__ __launch_bounds__(NTH) void prep_x(PX P) {
  __shared__ float T[64][65];
  const int bid = blockIdx.x;
  int e = 0;
  #pragma unroll
  for (int i = 1; i < 6; ++i) if (bid >= P.s[i].boff) e = i;
  const PXs sp = P.s[e];
  const int local = bid - sp.boff;
  const int p64 = local % sp.ptiles;
  const int t2  = local / sp.ptiles;
  const int Cq  = sp.C >> 6;
  const int c64 = t2 % Cq;
  const int bb  = t2 / Cq;

  const int tid = threadIdx.x;
  const int p0 = p64 << 6;
  const float* xs = sp.x + (size_t)(bb * sp.C + (c64 << 6)) * sp.HWp;
  const int tx = tid & 63, ty = tid >> 6;
  const int p = p0 + tx;
  const bool pok = p < sp.HWp;
  #pragma unroll
  for (int j = 0; j < 16; ++j) {
    int c = ty + (j << 2);
    T[c][tx] = pok ? xs[(size_t)c * sp.HWp + p] : 0.f;
  }
  __syncthreads();
  const int pl = tid >> 2, cs = (tid & 3) << 4;
  const int pg = p0 + pl;
  if (pg < sp.HWp) {
    unsigned short* dst = sp.xh + ((size_t)bb * sp.HWp + pg) * sp.C + (c64 << 6) + cs;
    short8 v0, v1;
    #pragma unroll
    for (int j = 0; j < 8; ++j) {
      v0[j] = (short)f2bf(T[cs + j][pl]);
      v1[j] = (short)f2bf(T[cs + 8 + j][pl]);
    }
    *(short8*)dst = v0;
    *(short8*)(dst + 8) = v1;
  }
}

// ---------------- prep_w: OIHW f32 -> [co][r*C+ci] bf16 ---------------------
struct PWs { const float *lw, *cw; unsigned short* wp; int C, lC, Nloc, Ntot, Kp; size_t tbase; };
struct PW { PWs s[6]; };

__global__ __launch_bounds__(NTH) void prep_w(PW P) {
  const size_t g = (size_t)blockIdx.x * NTH + threadIdx.x;
  int e = 0;
  #pragma unroll
  for (int i = 1; i < 6; ++i) if (g >= P.s[i].tbase) e = i;
  const PWs sp = P.s[e];
  const size_t local = g - sp.tbase;
  const int ci = (int)(local & (size_t)(sp.C - 1));
  const int co = (int)(local >> sp.lC);
  if (co >= sp.Ntot) return;
  const float* wr = (co < sp.Nloc)
      ? (sp.lw + ((size_t)co * sp.C + ci) * 9)
      : (sp.cw + ((size_t)(co - sp.Nloc) * sp.C + ci) * 9);
  unsigned short* dst = sp.wp + (size_t)co * sp.Kp + ci;
  float v[9];
  #pragma unroll
  for (int r = 0; r < 9; ++r) v[r] = wr[r];
  #pragma unroll
  for (int r = 0; r < 9; ++r) dst[(size_t)r * sp.C] = f2bf(v[r]);
}

// ---------------- main GEMM -------------------------------------------------
struct SG {
  const unsigned short *xh, *wp;
  const float *lb, *cb;
  int H, W, HWp, C, lCq, Cq, Kp, nb, M, Nloc, Ntot, abase, mtiles, ntiles, S, qPerS, boff;
};
struct AG { SG s[6]; const char* zeros; };

__global__ __launch_bounds__(NTH) void mbox_gemm(AG P, float* __restrict__ out) {
  __shared__ __align__(16) unsigned short A_s[128 * 64];
  __shared__ __align__(16) unsigned short B_s[128 * 64];

  const int bid = blockIdx.x;
  int e = 0;
  #pragma unroll
  for (int i = 1; i < 6; ++i) if (bid >= P.s[i].boff) e = i;
  const SG sp = P.s[e];
  const int local = bid - sp.boff;
  const int mtile = local % sp.mtiles;
  const int t2 = local / sp.mtiles;
  const int ntile = t2 % sp.ntiles;
  const int ks = t2 / sp.ntiles;

  const int tid = threadIdx.x, lane = tid & 63, wv = tid >> 6;
  const int wm = wv >> 1, wn = wv & 1;
  const int swz = ((lane & 7) ^ (lane >> 3)) << 4;   // byte offset, 16B chunks
  const int rsub = lane >> 3;

  // A-row geometry (4 rows per thread's wave-slice)
  int bA[4], hA[4], wA[4]; bool mok[4];
  #pragma unroll
  for (int i = 0; i < 4; ++i) {
    int row = (wv << 5) + (i << 3) + rsub;
    int mg = mtile * 128 + row;
    bool ok = mg < sp.M;
    int mc = ok ? mg : 0;
    int bb = mc / sp.HWp; int p = mc - bb * sp.HWp;
    int hh = p / sp.W;    int ww = p - hh * sp.W;
    bA[i] = bb; hA[i] = hh; wA[i] = ww; mok[i] = ok;
  }

  const int q0 = ks * sp.qPerS, q1 = q0 + sp.qPerS;

  const char* curB[4];
  #pragma unroll
  for (int i = 0; i < 4; ++i) {
    int row = (wv << 5) + (i << 3) + rsub;
    int nrow = ntile * 128 + row;                    // wp is padded: always valid
    curB[i] = (const char*)(sp.wp + (size_t)nrow * sp.Kp + (size_t)q0 * 64) + swz;
  }

  const char* curA[4];
  auto setA = [&](int rr, int cq0) {
    int d3 = rr / 3; int dh = d3 - 1, dw = rr - d3 * 3 - 1;
    #pragma unroll
    for (int i = 0; i < 4; ++i) {
      int hh = hA[i] + dh, ww = wA[i] + dw;
      bool ok = mok[i] & ((unsigned)hh < (unsigned)sp.H) & ((unsigned)ww < (unsigned)sp.W);
      const unsigned short* base = ok
          ? sp.xh + (((size_t)bA[i] * sp.H + hh) * sp.W + ww) * sp.C + (cq0 << 6)
          : (const unsigned short*)P.zeros;
      curA[i] = (const char*)base + swz;
    }
  };
  setA(q0 >> sp.lCq, q0 & (sp.Cq - 1));

  f32x4 acc[4][4] = {};
  const int l15 = lane & 15, lh = lane >> 4;

  for (int q = q0; q < q1; ++q) {
    #pragma unroll
    for (int i = 0; i < 4; ++i)
      gload_lds16(curA[i], (char*)A_s + ((wv << 5) + (i << 3)) * 128);
    #pragma unroll
    for (int i = 0; i < 4; ++i)
      gload_lds16(curB[i], (char*)B_s + ((wv << 5) + (i << 3)) * 128);
    #pragma unroll
    for (int i = 0; i < 4; ++i) { curA[i] += 128; curB[i] += 128; }
    __syncthreads();   // compiler drains vmcnt before barrier -> LDS ready
    #pragma unroll
    for (int kk = 0; kk < 2; ++kk) {
      const int klb = ((kk << 5) + (lh << 3)) << 1;  // byte k-offset
      short8 af[4], bv[4];
      #pragma unroll
      for (int mf = 0; mf < 4; ++mf) {
        int row = (wm << 6) + (mf << 4) + l15;
        af[mf] = *(const short8*)((const char*)A_s + row * 128 + (klb ^ ((row & 7) << 4)));
      }
      #pragma unroll
      for (int nf = 0; nf < 4; ++nf) {
        int row = (wn << 6) + (nf << 4) + l15;
        bv[nf] = *(const short8*)((const char*)B_s + row * 128 + (klb ^ ((row & 7) << 4)));
      }
      #pragma unroll
      for (int mf = 0; mf < 4; ++mf)
        #pragma unroll
        for (int nf = 0; nf < 4; ++nf)
          acc[mf][nf] = __builtin_amdgcn_mfma_f32_16x16x32_bf16(af[mf], bv[nf], acc[mf][nf], 0, 0, 0);
    }
    __syncthreads();   // all reads done before next stage overwrites
    if (((q + 1) & (sp.Cq - 1)) == 0 && (q + 1) < q1) setA((q + 1) >> sp.lCq, 0);
  }

  // epilogue
  const bool single = (sp.S == 1);
  const bool addbias = single || (ks == 0);
  #pragma unroll
  for (int nf = 0; nf < 4; ++nf) {
    const int ng = ntile * 128 + (wn << 6) + (nf << 4) + l15;
    const bool nvalid = ng < sp.Ntot;
    const bool isloc = ng < sp.Nloc;
    const int n2 = isloc ? ng : ng - sp.Nloc;
    const int ii = nvalid ? (n2 / sp.nb) : 0;
    const int rb = n2 - ii * sp.nb;
    float bias = nvalid ? (isloc ? sp.lb[n2] : sp.cb[n2]) : 0.f;
    if (!addbias) bias = 0.f;
    const int strd = isloc ? 4 : 81;
    const long ob0 = isloc ? 0l : (long)LOCTOT;
    #pragma unroll
    for (int mf = 0; mf < 4; ++mf) {
      #pragma unroll
      for (int rg = 0; rg < 4; ++rg) {
        const int mg = mtile * 128 + (wm << 6) + (mf << 4) + (lh << 2) + rg;
        if (nvalid && mg < sp.M) {
          const int bb = mg / sp.HWp; const int p = mg - bb * sp.HWp;
          const long oidx = ob0 + (long)(bb * ATOT + sp.abase + rb * sp.HWp + p) * strd + ii;
          const float v = acc[mf][nf][rg] + bias;
          if (single) out[oidx] = v;
          else        unsafeAtomicAdd(out + oidx, v);
        }
      }
    }
  }
}

// ---------------- host ------------------------------------------------------
extern "C" void kernel_launch(void* const* d_in, const int* in_sizes, int n_in,
                              void* d_out, int out_size, void* d_ws, size_t ws_size,
                              hipStream_t stream) {
  static const int CH[6]  = {512, 1024, 512, 256, 256, 256};
  static const int HH[6]  = {38, 19, 10, 5, 3, 1};
  static const int NB_[6] = {4, 6, 6, 6, 4, 4};
  static const int SK[6]  = {1, 8, 4, 4, 2, 2};        // split-K per scale
  static const int ORD[6] = {0, 1, 2, 4, 5, 3};        // gemm dispatch: long blocks first

  int abase[6]; { int a = 0; for (int s = 0; s < 6; ++s) { abase[s] = a; a += NB_[s] * HH[s] * HH[s]; } }

  // ws layout: [xh 0..5][wp 0..5][zeros 8KB]
  size_t xh_off[6], wp_off[6], off = 0;
  for (int s = 0; s < 6; ++s) { xh_off[s] = off; off += (size_t)8 * HH[s] * HH[s] * CH[s] * 2; }
  const size_t wp_base = off;
  for (int s = 0; s < 6; ++s) {
    wp_off[s] = off;
    int Ntot = NB_[s] * 85;
    int Npad = ((Ntot + 127) / 128) * 128;
    off += (size_t)Npad * (CH[s] * 9) * 2;
  }
  const size_t zeros_off = off; off += 8192;
  (void)ws_size;  // requires ~40.4 MB of ws

  char* ws = (char*)d_ws;
  hipMemsetAsync(d_out, 0, (size_t)out_size * sizeof(float), stream);
  hipMemsetAsync(ws + wp_base, 0, zeros_off + 8192 - wp_base, stream);

  // prep_x
  PX px; int pxb = 0;
  for (int s = 0; s < 6; ++s) {
    PXs& p = px.s[s];
    p.x = (const float*)d_in[5 * s + 0];
    p.xh = (unsigned short*)(ws + xh_off[s]);
    p.C = CH[s]; p.HWp = HH[s] * HH[s];
    p.ptiles = (p.HWp + 63) / 64;
    p.boff = pxb;
    pxb += 8 * (CH[s] >> 6) * p.ptiles;
  }
  hipLaunchKernelGGL(prep_x, dim3(pxb), dim3(NTH), 0, stream, px);

  // prep_w
  PW pw; size_t tb = 0;
  for (int s = 0; s < 6; ++s) {
    PWs& p = pw.s[s];
    p.lw = (const float*)d_in[5 * s + 1];
    p.cw = (const float*)d_in[5 * s + 3];
    p.wp = (unsigned short*)(ws + wp_off[s]);
    p.C = CH[s];
    p.lC = (CH[s] == 1024) ? 10 : (CH[s] == 512 ? 9 : 8);
    p.Nloc = NB_[s] * 4; p.Ntot = NB_[s] * 85;
    p.Kp = CH[s] * 9;
    p.tbase = tb;
    tb += (size_t)p.Ntot * CH[s];
  }
  hipLaunchKernelGGL(prep_w, dim3((unsigned)((tb + NTH - 1) / NTH)), dim3(NTH), 0, stream, pw);

  // gemm
  AG ag; ag.zeros = ws + zeros_off;
  int boff = 0;
  for (int oi = 0; oi < 6; ++oi) {
    int s = ORD[oi];
    SG& g = ag.s[oi];
    g.xh = (const unsigned short*)(ws + xh_off[s]);
    g.wp = (const unsigned short*)(ws + wp_off[s]);
    g.lb = (const float*)d_in[5 * s + 2];
    g.cb = (const float*)d_in[5 * s + 4];
    g.H = HH[s]; g.W = HH[s]; g.HWp = HH[s] * HH[s]; g.C = CH[s];
    g.Cq = CH[s] >> 6;
    g.lCq = (g.Cq == 16) ? 4 : (g.Cq == 8 ? 3 : 2);
    g.Kp = CH[s] * 9;
    g.nb = NB_[s];
    g.M = 8 * g.HWp;
    g.Nloc = NB_[s] * 4; g.Ntot = NB_[s] * 85;
    g.abase = abase[s];
    g.mtiles = (g.M + 127) / 128;
    g.ntiles = (g.Ntot + 127) / 128;
    g.S = SK[s];
    g.qPerS = (9 * g.Cq) / SK[s];
    g.boff = boff;
    boff += g.mtiles * g.ntiles * g.S;
  }
  hipLaunchKernelGGL(mbox_gemm, dim3(boff), dim3(NTH), 0, stream, ag, (float*)d_out);
}